// Round 7
// baseline (71.803 us; speedup 1.0000x reference)
//
#include <hip/hip_runtime.h>

// AdderNet 2D: out[n,f,h,w] = -sum_{c,kh,kw} |W[f,c,kh,kw] - xpad[n,c,h+kh,w+kw]|
// x: (16,64,14,14) fp32, W: (64,64,3,3) fp32, out: (16,64,14,14) fp32
//
// R7: R6's per-wave body (lane = f, W in 36 VGPRs loaded once, x rows via
// wave-uniform loads, 14 pixel accs in regs) but 256-thread blocks so the
// compiler is NOT capped at 128 VGPR (R4/R6's 1024-thr blocks forced the
// cap -> suspected scratch spills), and channels split across blocks:
// grid = (14 row, 16 n, 4 cslice) = 896 blocks = 3.5/CU for latency
// hiding. Cross-block channel reduce = fp32 atomicAdd onto memset-zeroed
// d_out (4-way contention, device-scope HW atomic).

#define N_ 16
#define C_ 64
#define F_ 64
#define P_ 196

__global__ __launch_bounds__(256) void adder2d_kernel(
    const float* __restrict__ x, const float* __restrict__ w,
    float* __restrict__ out)
{
    __shared__ float part[4][64 * 15];   // 15,360 B, stride 15 -> conflict-free

    const int tid = threadIdx.x;        // 0..255
    const int row = blockIdx.x;         // 0..13 output row
    const int n   = blockIdx.y;         // 0..15
    const int cs  = blockIdx.z;         // 0..3 channel slice (16 ch)
    const int f   = tid & 63;           // lane = filter
    const int wid = __builtin_amdgcn_readfirstlane(tid >> 6);  // wave 0..3
    const int cbase = cs * 16 + wid * 4;  // this wave's 4 channels

    // ---- W[f][cbase..cbase+3][0..8]: 36 contiguous floats, loaded once ----
    float Wr[36];
    {
        const float4* wp = (const float4*)(w + f * (C_ * 9) + cbase * 9);
        #pragma unroll
        for (int i = 0; i < 9; ++i) {
            float4 t = wp[i];
            Wr[4 * i + 0] = t.x; Wr[4 * i + 1] = t.y;
            Wr[4 * i + 2] = t.z; Wr[4 * i + 3] = t.w;
        }
    }

    float acc[14];
    #pragma unroll
    for (int p = 0; p < 14; ++p) acc[p] = 0.f;

    // ---- hot loop: 4 channels x 3 kh rows; x row is wave-uniform ----
    #pragma unroll
    for (int cl = 0; cl < 4; ++cl) {
        const float* xc = x + (n * C_ + (cbase + cl)) * P_;
        #pragma unroll
        for (int kh = 0; kh < 3; ++kh) {
            const int ir = row + kh - 1;           // input row, -1..14
            float xr[16];
            xr[0] = 0.f; xr[15] = 0.f;
            if (ir >= 0 && ir <= 13) {             // block-uniform branch
                #pragma unroll
                for (int j = 0; j < 14; ++j) xr[j + 1] = xc[ir * 14 + j];
            } else {
                #pragma unroll
                for (int j = 0; j < 14; ++j) xr[j + 1] = 0.f;
            }
            #pragma unroll
            for (int kw = 0; kw < 3; ++kw) {
                const float wvv = Wr[cl * 9 + kh * 3 + kw];
                #pragma unroll
                for (int p = 0; p < 14; ++p)
                    acc[p] += fabsf(wvv - xr[p + kw]);  // subrev + add|.|
            }
        }
    }

    // ---- 4-wave partial reduce in LDS ----
    #pragma unroll
    for (int p = 0; p < 14; ++p) part[wid][f * 15 + p] = acc[p];
    __syncthreads();

    // ---- 896 outputs this block; atomic add into zeroed d_out ----
    for (int o = tid; o < 896; o += 256) {
        const int ff = o / 14;
        const int px = o - ff * 14;
        const int a  = ff * 15 + px;
        float s = part[0][a] + part[1][a] + part[2][a] + part[3][a];
        atomicAdd(&out[(n * F_ + ff) * P_ + row * 14 + px], -s);
    }
}

extern "C" void kernel_launch(void* const* d_in, const int* in_sizes, int n_in,
                              void* d_out, int out_size, void* d_ws, size_t ws_size,
                              hipStream_t stream) {
    const float* x = (const float*)d_in[0];
    const float* w = (const float*)d_in[1];
    float* out = (float*)d_out;
    // d_out is re-poisoned 0xAA before every call -> zero it (graph-legal)
    hipMemsetAsync(out, 0, (size_t)out_size * sizeof(float), stream);
    dim3 grid(14, N_, 4);
    adder2d_kernel<<<grid, 256, 0, stream>>>(x, w, out);
}